// Round 1
// baseline (330.723 us; speedup 1.0000x reference)
//
#include <hip/hip_runtime.h>
#include <math.h>

#define B_ 8
#define L_ 96
#define D_ 512
#define R_ 64
#define NT_ 47
#define NL_ 3

// ws layout (float offsets)
#define SEQ_OFF   0
#define AGG_OFF   393216            // B*L*D
#define G_OFF     786432            // 47*47 = 2209 (pad 2304)
#define SDEP_OFF  788736            // B*L*L = 73728
#define POOL_OFF  862464            // NL*B*D = 12288
#define ENSW_OFF  874752            // 3 (+pad)
#define CNT_OFF   874756            // B
// total = 874764 floats = ~3.5 MB

// ---------------------------------------------------------------------------
// prep1: fused (a) seq = text*gamma/sqrt(1+eps)+beta  (blocks [0,384))
//              (b) G[t1,t2] = dot(E[t1],E[t2])        (blocks [384,2593))
//              (c) ensemble softmax + mask counts      (block 2593)
// ---------------------------------------------------------------------------
__global__ __launch_bounds__(256) void k_prep1(
    const float* __restrict__ text, const float* __restrict__ mask,
    const float* __restrict__ E, const float* __restrict__ gamma,
    const float* __restrict__ beta, const float* __restrict__ ensl,
    float* __restrict__ ws)
{
  __shared__ float red[4];
  const int blk = blockIdx.x;
  const int tid = threadIdx.x;
  if (blk < 384) {
    // 98304 float4 total
    const int idx = blk * 256 + tid;
    const float inv = 0.9995003746879289f;   // 1/sqrt(1+0.001)
    float4 t4 = ((const float4*)text)[idx];
    const int g4i = idx & (D_/4 - 1);
    float4 g4 = ((const float4*)gamma)[g4i];
    float4 b4 = ((const float4*)beta)[g4i];
    float4 o;
    o.x = t4.x * (g4.x * inv) + b4.x;
    o.y = t4.y * (g4.y * inv) + b4.y;
    o.z = t4.z * (g4.z * inv) + b4.z;
    o.w = t4.w * (g4.w * inv) + b4.w;
    ((float4*)(ws + SEQ_OFF))[idx] = o;
  } else if (blk < 384 + NT_*NT_) {
    const int g = blk - 384;
    const int t1 = g / NT_, t2 = g % NT_;
    const float* e1 = E + t1 * D_;
    const float* e2 = E + t2 * D_;
    float p = e1[tid] * e2[tid] + e1[tid + 256] * e2[tid + 256];
    #pragma unroll
    for (int o = 32; o; o >>= 1) p += __shfl_xor(p, o);
    if ((tid & 63) == 0) red[tid >> 6] = p;
    __syncthreads();
    if (tid == 0) (ws + G_OFF)[g] = red[0] + red[1] + red[2] + red[3];
  } else {
    if (tid < B_) {
      int c = 0;
      for (int i = 0; i < L_; ++i) c += (mask[tid * L_ + i] != 0.f);
      (ws + CNT_OFF)[tid] = 1.0f / ((float)c + 1e-10f);
    }
    if (tid == 64) {
      float e0 = ensl[0], e1 = ensl[1], e2 = ensl[2];
      float m = fmaxf(e0, fmaxf(e1, e2));
      float x0 = expf(e0 - m), x1 = expf(e1 - m), x2 = expf(e2 - m);
      float s = x0 + x1 + x2;
      (ws + ENSW_OFF)[0] = x0 / s;
      (ws + ENSW_OFF)[1] = x1 / s;
      (ws + ENSW_OFF)[2] = x2 / s;
    }
  }
}

// ---------------------------------------------------------------------------
// sdep: S[b,i,j] = (v_ij>0 && v_ji>0) ? G[v_ij,v_ji] : 0   (layer-invariant)
// ---------------------------------------------------------------------------
__global__ __launch_bounds__(256) void k_sdep(
    const int* __restrict__ dv, float* __restrict__ ws)
{
  const float* G = ws + G_OFF;
  float* S = ws + SDEP_OFF;
  const int idx = blockIdx.x * 256 + threadIdx.x;   // < 73728
  const int b = idx / (L_ * L_);
  const int r = idx % (L_ * L_);
  const int i = r / L_, j = r % L_;
  const int v1 = dv[idx];
  const int v2 = dv[b * L_ * L_ + j * L_ + i];
  S[idx] = (v1 > 0 && v2 > 0) ? G[v1 * NT_ + v2] : 0.f;
}

// ---------------------------------------------------------------------------
// attn: per block 4 query rows. score -> softmax -> attn*adj -> agg
// agg[b,i,d] = sum_j attn * (seq[b,j,d] + (v_ji>0 ? E[v_ji,d] : 0))
// ---------------------------------------------------------------------------
__global__ __launch_bounds__(256) void k_attn(
    const float* __restrict__ seq, const float* __restrict__ adj,
    const int* __restrict__ dv, const float* __restrict__ E,
    const float* __restrict__ sdep, float* __restrict__ agg)
{
  __shared__ float s_q[4 * D_];
  __shared__ float s_sc[4 * L_];
  __shared__ float s_at[4 * L_];
  __shared__ int   s_vt[4 * L_];
  const int blk = blockIdx.x;       // 0..191
  const int b = blk / (L_ / 4);
  const int i0 = (blk % (L_ / 4)) * 4;
  const int tid = threadIdx.x;
  const int w = tid >> 6, lane = tid & 63;

  { // 4 contiguous q rows -> LDS
    const float4* src = (const float4*)(seq + (b * L_ + i0) * D_);
    float4* dst = (float4*)s_q;
    dst[tid] = src[tid];
    dst[tid + 256] = src[tid + 256];
  }
  // transposed dep_value: s_vt[ii*96+j] = dv[b, j, i0+ii]
  for (int idx = tid; idx < 4 * L_; idx += 256) {
    const int ii = idx & 3, j = idx >> 2;
    s_vt[ii * L_ + j] = dv[(b * L_ + j) * L_ + i0 + ii];
  }
  __syncthreads();

  // phase 2: raw dots, wave w handles j = w, w+4, ...
  for (int j = w; j < L_; j += 4) {
    const float* kr = seq + (b * L_ + j) * D_;
    float d0 = 0.f, d1 = 0.f, d2 = 0.f, d3 = 0.f;
    #pragma unroll
    for (int k = 0; k < D_; k += 64) {
      const float v = kr[k + lane];
      d0 = fmaf(s_q[0 * D_ + k + lane], v, d0);
      d1 = fmaf(s_q[1 * D_ + k + lane], v, d1);
      d2 = fmaf(s_q[2 * D_ + k + lane], v, d2);
      d3 = fmaf(s_q[3 * D_ + k + lane], v, d3);
    }
    #pragma unroll
    for (int o = 32; o; o >>= 1) {
      d0 += __shfl_xor(d0, o);
      d1 += __shfl_xor(d1, o);
      d2 += __shfl_xor(d2, o);
      d3 += __shfl_xor(d3, o);
    }
    if (lane == 0) {
      s_sc[0 * L_ + j] = d0; s_sc[1 * L_ + j] = d1;
      s_sc[2 * L_ + j] = d2; s_sc[3 * L_ + j] = d3;
    }
  }
  __syncthreads();

  // phase 3: softmax per wave (wave w owns row i0+w), then *adj
  {
    const float scale = 0.044194173824159216f;  // 1/sqrt(512)
    const int i = i0 + w;
    const float* sd = sdep + (b * L_ + i) * L_;
    const float* ad = adj + (b * L_ + i) * L_;
    float v0 = (s_sc[w * L_ + lane] + sd[lane]) * scale;
    float v1 = (lane < 32) ? (s_sc[w * L_ + 64 + lane] + sd[64 + lane]) * scale
                           : -3.0e38f;
    float m = fmaxf(v0, v1);
    #pragma unroll
    for (int o = 32; o; o >>= 1) m = fmaxf(m, __shfl_xor(m, o));
    float e0 = expf(v0 - m);
    float e1 = (lane < 32) ? expf(v1 - m) : 0.f;
    float s = e0 + e1;
    #pragma unroll
    for (int o = 32; o; o >>= 1) s += __shfl_xor(s, o);
    const float inv = 1.f / s;
    s_at[w * L_ + lane] = e0 * inv * ad[lane];
    if (lane < 32) s_at[w * L_ + 64 + lane] = e1 * inv * ad[64 + lane];
  }
  __syncthreads();

  // phase 4: agg, wave w owns row i0+w; lane covers d = lane + 64t
  {
    float acc[8];
    #pragma unroll
    for (int t = 0; t < 8; ++t) acc[t] = 0.f;
    for (int j = 0; j < L_; ++j) {
      const float a = s_at[w * L_ + j];
      if (a != 0.f) {                       // wave-uniform: ~10/96 taken
        const float* kr = seq + (b * L_ + j) * D_;
        const int v = s_vt[w * L_ + j];
        if (v > 0) {
          const float* er = E + v * D_;
          #pragma unroll
          for (int t = 0; t < 8; ++t)
            acc[t] = fmaf(a, kr[lane + 64 * t] + er[lane + 64 * t], acc[t]);
        } else {
          #pragma unroll
          for (int t = 0; t < 8; ++t)
            acc[t] = fmaf(a, kr[lane + 64 * t], acc[t]);
        }
      }
    }
    float* outp = agg + (b * L_ + i0 + w) * D_;
    #pragma unroll
    for (int t = 0; t < 8; ++t) outp[lane + 64 * t] = acc[t];
  }
}

// ---------------------------------------------------------------------------
// gemm: Out = relu(A @ W + bias), A:(768,512) W:(512,512)
// block: 8 rows x 128 cols; A tile + W chunk staged in LDS
// ---------------------------------------------------------------------------
__global__ __launch_bounds__(256) void k_gemm(
    const float* __restrict__ A, const float* __restrict__ W,
    const float* __restrict__ bias, float* __restrict__ Out)
{
  __shared__ float s_a[8 * D_];       // 16 KB
  __shared__ float s_w[64 * 128];     // 32 KB
  const int rt = blockIdx.x;          // 0..95
  const int ct = blockIdx.y;          // 0..3
  const int tid = threadIdx.x;
  const int r0 = rt * 8;
  {
    const float4* a4 = (const float4*)(A + r0 * D_);
    float4* s4 = (float4*)s_a;
    s4[tid] = a4[tid];
    s4[tid + 256] = a4[tid + 256];
    s4[tid + 512] = a4[tid + 512];
    s4[tid + 768] = a4[tid + 768];
  }
  const int c = tid & 127;
  const int col = ct * 128 + c;
  const int rg = (tid >> 7) * 4;      // 0 or 4
  float acc0 = 0.f, acc1 = 0.f, acc2 = 0.f, acc3 = 0.f;
  const float* a0p = s_a + (rg + 0) * D_;
  const float* a1p = s_a + (rg + 1) * D_;
  const float* a2p = s_a + (rg + 2) * D_;
  const float* a3p = s_a + (rg + 3) * D_;
  for (int kc = 0; kc < D_; kc += 64) {
    __syncthreads();
    {
      const float4* wsrc = (const float4*)(W + kc * D_ + ct * 128);
      float4* wd = (float4*)s_w;
      #pragma unroll
      for (int t = 0; t < 8; ++t) {
        const int idx = tid + t * 256;      // 0..2047
        const int k = idx >> 5, c4 = idx & 31;
        wd[idx] = wsrc[k * 128 + c4];       // W row stride = 512 fl = 128 f4
      }
    }
    __syncthreads();
    #pragma unroll 4
    for (int k = 0; k < 64; ++k) {
      const float wv = s_w[k * 128 + c];
      acc0 = fmaf(a0p[kc + k], wv, acc0);
      acc1 = fmaf(a1p[kc + k], wv, acc1);
      acc2 = fmaf(a2p[kc + k], wv, acc2);
      acc3 = fmaf(a3p[kc + k], wv, acc3);
    }
  }
  const float bv = bias[col];
  Out[(r0 + rg + 0) * D_ + col] = fmaxf(acc0 + bv, 0.f);
  Out[(r0 + rg + 1) * D_ + col] = fmaxf(acc1 + bv, 0.f);
  Out[(r0 + rg + 2) * D_ + col] = fmaxf(acc2 + bv, 0.f);
  Out[(r0 + rg + 3) * D_ + col] = fmaxf(acc3 + bv, 0.f);
}

// ---------------------------------------------------------------------------
// pool: pools[b,d] = (sum_i mask*seq) * rcnt[b]
// ---------------------------------------------------------------------------
__global__ __launch_bounds__(256) void k_pool(
    const float* __restrict__ seq, const float* __restrict__ mask,
    const float* __restrict__ ws, float* __restrict__ pool)
{
  const float* rcnt = ws + CNT_OFF;
  const int b = blockIdx.x >> 1;
  const int d = (blockIdx.x & 1) * 256 + threadIdx.x;
  float acc = 0.f;
  for (int i = 0; i < L_; ++i) {
    const float m = mask[b * L_ + i];
    if (m != 0.f) acc += m * seq[(b * L_ + i) * D_ + d];
  }
  pool[b * D_ + d] = acc * rcnt[b];
}

// ---------------------------------------------------------------------------
// final: ens = sum_l w_l * pool_l ; out = ens @ fcW + fcb
// ---------------------------------------------------------------------------
__global__ __launch_bounds__(64) void k_final(
    const float* __restrict__ ws, const float* __restrict__ fcW,
    const float* __restrict__ fcb, float* __restrict__ out)
{
  const int b = blockIdx.x, r = threadIdx.x;
  const float* ensw = ws + ENSW_OFF;
  const float w0 = ensw[0], w1 = ensw[1], w2 = ensw[2];
  const float* p0 = ws + POOL_OFF + b * D_;
  const float* p1 = ws + POOL_OFF + (B_ + b) * D_;
  const float* p2 = ws + POOL_OFF + (2 * B_ + b) * D_;
  float acc = fcb[r];
  for (int d = 0; d < D_; ++d) {
    const float e = w0 * p0[d] + w1 * p1[d] + w2 * p2[d];
    acc = fmaf(e, fcW[d * R_ + r], acc);
  }
  out[b * R_ + r] = acc;
}

extern "C" void kernel_launch(void* const* d_in, const int* in_sizes, int n_in,
                              void* d_out, int out_size, void* d_ws, size_t ws_size,
                              hipStream_t stream)
{
  const float* text  = (const float*)d_in[0];
  const float* mask  = (const float*)d_in[1];
  const float* adj   = (const float*)d_in[2];
  const float* E     = (const float*)d_in[3];
  const float* gamma = (const float*)d_in[4];
  const float* beta  = (const float*)d_in[5];
  const float* Wst   = (const float*)d_in[6];
  const float* bst   = (const float*)d_in[7];
  const float* ensl  = (const float*)d_in[8];
  const float* fcW   = (const float*)d_in[9];
  const float* fcb   = (const float*)d_in[10];
  const int*   dv    = (const int*)d_in[11];
  float* ws  = (float*)d_ws;
  float* out = (float*)d_out;

  float* seq = ws + SEQ_OFF;
  float* agg = ws + AGG_OFF;

  k_prep1<<<dim3(384 + NT_*NT_ + 1), dim3(256), 0, stream>>>(
      text, mask, E, gamma, beta, ensl, ws);
  k_sdep<<<dim3((B_*L_*L_)/256), dim3(256), 0, stream>>>(dv, ws);

  for (int l = 0; l < NL_; ++l) {
    k_attn<<<dim3(B_ * L_ / 4), dim3(256), 0, stream>>>(
        seq, adj, dv, E, ws + SDEP_OFF, agg);
    k_gemm<<<dim3(L_ * B_ / 8, 4), dim3(256), 0, stream>>>(
        agg, Wst + l * D_ * D_, bst + l * D_, seq);
    k_pool<<<dim3(2 * B_), dim3(256), 0, stream>>>(
        seq, mask, ws, ws + POOL_OFF + l * B_ * D_);
  }
  k_final<<<dim3(B_), dim3(64), 0, stream>>>(ws, fcW, fcb, out);
}